// Round 4
// baseline (349.228 us; speedup 1.0000x reference)
//
#include <hip/hip_runtime.h>
#include <hip/hip_bf16.h>

#define B_   16
#define T_   243
#define J_   17
#define BJ_  (B_ * J_)   // 272
#define NCH  8           // t-chunks per bj
#define TC   32          // q rows per chunk
#define KVR  48          // s/v rows per block (32 + 6 halo, padded to 48)

typedef __bf16 bf16x8 __attribute__((ext_vector_type(8)));
typedef float  f32x4  __attribute__((ext_vector_type(4)));

static __device__ __forceinline__ float bf2f(unsigned short u) {
  unsigned int v = ((unsigned int)u) << 16;
  return __builtin_bit_cast(float, v);
}
static __device__ __forceinline__ unsigned short f2bf(float f) {
  __hip_bfloat16 h = __float2bfloat16(f);
  return __builtin_bit_cast(unsigned short, h);
}
static __device__ __forceinline__ float wave_sum(float v) {
  v += __shfl_xor(v, 1);  v += __shfl_xor(v, 2);  v += __shfl_xor(v, 4);
  v += __shfl_xor(v, 8);  v += __shfl_xor(v, 16); v += __shfl_xor(v, 32);
  return v;
}

// ---------------------------------------------------------------------------
// K0: Wv (fp32 [n][c]) -> bf16 [n][c]
// ---------------------------------------------------------------------------
__global__ void wv_kernel(const float* __restrict__ Wv,
                          unsigned short* __restrict__ wv) {
  int idx = blockIdx.x * 256 + threadIdx.x;
  wv[idx] = f2bf(Wv[idx]);
}

// ---------------------------------------------------------------------------
// K1: Gram matrix Gt[d][c] = G[c][d] = sum_i Wq[i][c] * Wk[i][d]  (bf16)
// block = d (Wk column, uniform scalar), thread = c (coalesced).
// ---------------------------------------------------------------------------
__global__ __launch_bounds__(256) void gram_kernel(
    const float* __restrict__ Wq, const float* __restrict__ Wk,
    unsigned short* __restrict__ gt) {
  int d = blockIdx.x, c = threadIdx.x;
  float acc = 0.f;
#pragma unroll 8
  for (int i = 0; i < 256; ++i)
    acc += Wq[i * 256 + c] * Wk[i * 256 + d];
  gt[d * 256 + c] = f2bf(acc);
}

// ---------------------------------------------------------------------------
// K2: w1[c]=sum_i Wk[i][c]*bq[i]; w2[c]=sum_i Wq[i][c]*bk[i]; bqk=bq.bk (fp32)
// ---------------------------------------------------------------------------
__global__ __launch_bounds__(256) void wvec_kernel(
    const float* __restrict__ Wq, const float* __restrict__ Wk,
    const float* __restrict__ bq, const float* __restrict__ bk,
    float* __restrict__ w1v, float* __restrict__ w2v,
    float* __restrict__ bqkp) {
  __shared__ float red[4];
  int c = threadIdx.x;
  float a1 = 0.f, a2 = 0.f;
#pragma unroll 8
  for (int i = 0; i < 256; ++i) {
    a1 += Wk[i * 256 + c] * bq[i];
    a2 += Wq[i * 256 + c] * bk[i];
  }
  w1v[c] = a1;
  w2v[c] = a2;
  float p = wave_sum(bq[c] * bk[c]);
  if ((c & 63) == 0) red[c >> 6] = p;
  __syncthreads();
  if (c == 0) bqkp[0] = red[0] + red[1] + red[2] + red[3];
}

// ---------------------------------------------------------------------------
// K3: fully fused. Block = (chunk, bj), 256 threads (4 waves).
// A: spatial rows (48, clamped halo) -> sS (swizzled) + beta1/beta2 scalars
// BC: v = s@Wv^T + bv -> vL;  sg = s_q@G -> sG (swizzled). B-frags straight
//     from L2 (wv/gt) - no LDS staging, no staging barriers.
// D: Sband = sg@s^T (MFMA) + betas + bqk, scaled 1/(16 tau) -> Sb (fp32)
// E: per q-row: lane-redundant softmax over 7 banded logits (boundary mask),
//    7-term AXPY over vL, exp_map0, coalesced out write.
// Barriers: 3 total.
// ---------------------------------------------------------------------------
__global__ __launch_bounds__(256) void fused_kernel(
    const float* __restrict__ x, const unsigned short* __restrict__ wv,
    const unsigned short* __restrict__ gt, const float* __restrict__ w1v,
    const float* __restrict__ w2v, const float* __restrict__ bqkp,
    const float* __restrict__ bv, const float* __restrict__ tau,
    float* __restrict__ out) {
  __shared__ __align__(16) unsigned short sS[KVR * 256];  // 24.0 KB swizzled
  __shared__ __align__(16) unsigned short vL[KVR * 264];  // 24.75 KB stride-264
  __shared__ __align__(16) unsigned short sG[TC * 256];   // 16.0 KB swizzled
  __shared__ __align__(16) float Sb[TC * 52];             // 6.5 KB
  __shared__ float beta1[KVR], beta2[KVR];

  int tid = threadIdx.x, w = tid >> 6, lane = tid & 63;
  int ch = blockIdx.x, bj = blockIdx.y;
  int b = bj / J_, j = bj % J_;
  int t0 = ch * TC;

  float isc = 1.f / (16.f * fmaxf(tau[0], 1e-3f));
  float bqk = bqkp[0];
  float4 w1r = *(const float4*)(w1v + lane * 4);
  float4 w2r = *(const float4*)(w2v + lane * 4);

  char* sB = (char*)sS;
  char* gB = (char*)sG;

  // ---- Phase A: spatial + beta dots ------------------------------------
  for (int rr = 0; rr < 12; ++rr) {
    int r = w * 12 + rr;                       // 0..47
    int ts = t0 - 3 + r;
    ts = min(max(ts, 0), T_ - 1);              // edge-pad clamp
    const float* xr = x + ((size_t)((b * T_ + ts) * J_ + j)) * 257;
    float xs0 = xr[1 + lane * 4], xs1 = xr[2 + lane * 4];
    float xs2 = xr[3 + lane * 4], xs3 = xr[4 + lane * 4];
    float ss = xs0 * xs0 + xs1 * xs1 + xs2 * xs2 + xs3 * xs3;
    float s1 = w1r.x * xs0 + w1r.y * xs1 + w1r.z * xs2 + w1r.w * xs3;
    float s2 = w2r.x * xs0 + w2r.y * xs1 + w2r.z * xs2 + w2r.w * xs3;
#pragma unroll
    for (int sh = 1; sh < 64; sh <<= 1) {      // 3 interleaved butterflies
      ss += __shfl_xor(ss, sh);
      s1 += __shfl_xor(s1, sh);
      s2 += __shfl_xor(s2, sh);
    }
    float xn = fmaxf(sqrtf(ss), 1e-7f);
    float alpha = acoshf(fmaxf(xr[0], 1.f + 1e-7f)) / xn;
    ushort4 o;
    o.x = f2bf(xs0 * alpha); o.y = f2bf(xs1 * alpha);
    o.z = f2bf(xs2 * alpha); o.w = f2bf(xs3 * alpha);
    *(ushort4*)(sB + r * 512 + ((lane * 8) ^ ((r & 7) << 4))) = o;
    if (lane == 0) { beta1[r] = alpha * s1; beta2[r] = alpha * s2; }
  }
  __syncthreads();

  int fr = lane & 15, fq = lane >> 4;
  int nb = w * 64;                              // this wave's 64-col slice

  // ---- Phase B: v GEMM (48 rows x 64 cols x K=256) ----------------------
  {
    f32x4 av[3][4] = {};
#pragma unroll
    for (int kk = 0; kk < 8; ++kk) {
      bf16x8 bfr[4];
#pragma unroll
      for (int ni = 0; ni < 4; ++ni)
        bfr[ni] = *(const bf16x8*)(wv + (size_t)(nb + ni * 16 + fr) * 256 +
                                   kk * 32 + fq * 8);
      bf16x8 a[3];
#pragma unroll
      for (int mi = 0; mi < 3; ++mi) {
        int r = mi * 16 + fr;
        a[mi] = *(const bf16x8*)(sB + r * 512 +
                                 ((kk * 64 + fq * 16) ^ ((r & 7) << 4)));
      }
#pragma unroll
      for (int mi = 0; mi < 3; ++mi)
#pragma unroll
        for (int ni = 0; ni < 4; ++ni)
          av[mi][ni] = __builtin_amdgcn_mfma_f32_16x16x32_bf16(
              a[mi], bfr[ni], av[mi][ni], 0, 0, 0);
    }
#pragma unroll
    for (int ni = 0; ni < 4; ++ni) {
      int col = nb + ni * 16 + fr;
      float bb = bv[col];
#pragma unroll
      for (int mi = 0; mi < 3; ++mi)
#pragma unroll
        for (int r2 = 0; r2 < 4; ++r2) {
          int tr = mi * 16 + fq * 4 + r2;
          vL[tr * 264 + col] = f2bf(av[mi][ni][r2] + bb);
        }
    }
  }

  // ---- Phase C: sg = s_q @ G (32 rows x 64 cols x K=256) ----------------
  {
    f32x4 ag[2][4] = {};
#pragma unroll
    for (int kk = 0; kk < 8; ++kk) {
      bf16x8 bfr[4];
#pragma unroll
      for (int ni = 0; ni < 4; ++ni)
        bfr[ni] = *(const bf16x8*)(gt + (size_t)(nb + ni * 16 + fr) * 256 +
                                   kk * 32 + fq * 8);
      bf16x8 a[2];
#pragma unroll
      for (int mi = 0; mi < 2; ++mi) {
        int r = 3 + mi * 16 + fr;               // q rows offset +3 in s
        a[mi] = *(const bf16x8*)(sB + r * 512 +
                                 ((kk * 64 + fq * 16) ^ ((r & 7) << 4)));
      }
#pragma unroll
      for (int mi = 0; mi < 2; ++mi)
#pragma unroll
        for (int ni = 0; ni < 4; ++ni)
          ag[mi][ni] = __builtin_amdgcn_mfma_f32_16x16x32_bf16(
              a[mi], bfr[ni], ag[mi][ni], 0, 0, 0);
    }
#pragma unroll
    for (int ni = 0; ni < 4; ++ni) {
      int d = nb + ni * 16 + fr;
#pragma unroll
      for (int mi = 0; mi < 2; ++mi)
#pragma unroll
        for (int r2 = 0; r2 < 4; ++r2) {
          int qr = mi * 16 + fq * 4 + r2;
          *(unsigned short*)(gB + qr * 512 + ((d * 2) ^ ((qr & 7) << 4))) =
              f2bf(ag[mi][ni][r2]);
        }
    }
  }
  __syncthreads();

  // ---- Phase D: Sband = sg @ s^T (2x3 tiles of 16x16) + betas -----------
  for (int idx = w; idx < 6; idx += 4) {
    int mi = idx / 3, nj = idx % 3;
    f32x4 acc = {};
#pragma unroll
    for (int kk = 0; kk < 8; ++kk) {
      int ra = mi * 16 + fr;
      bf16x8 a = *(const bf16x8*)(gB + ra * 512 +
                                  ((kk * 64 + fq * 16) ^ ((ra & 7) << 4)));
      int rb = nj * 16 + fr;
      bf16x8 bb = *(const bf16x8*)(sB + rb * 512 +
                                   ((kk * 64 + fq * 16) ^ ((rb & 7) << 4)));
      acc = __builtin_amdgcn_mfma_f32_16x16x32_bf16(a, bb, acc, 0, 0, 0);
    }
#pragma unroll
    for (int r2 = 0; r2 < 4; ++r2) {
      int qr = mi * 16 + fq * 4 + r2;
      int tp = nj * 16 + fr;
      Sb[qr * 52 + tp] = (acc[r2] + beta1[tp] + beta2[3 + qr] + bqk) * isc;
    }
  }
  __syncthreads();

  // ---- Phase E: softmax + PV AXPY + exp_map0 + store --------------------
  for (int rr = 0; rr < 8; ++rr) {
    int qt = w * 8 + rr;
    int t = t0 + qt;
    if (t >= T_) break;                         // wave-uniform

    float pw[7];
    float mx = -1e30f;
#pragma unroll
    for (int k7 = 0; k7 < 7; ++k7) {
      int frame = t + k7 - 3;
      float lg = (frame >= 0 && frame < T_) ? Sb[qt * 52 + qt + k7] : -1e30f;
      pw[k7] = lg;
      mx = fmaxf(mx, lg);
    }
    float sum = 0.f;
#pragma unroll
    for (int k7 = 0; k7 < 7; ++k7) {
      float e = expf(pw[k7] - mx);              // masked -> exp(~-1e30) = 0
      pw[k7] = e;
      sum += e;
    }
    float inv = 1.f / sum;

    float a0 = 0.f, a1 = 0.f, a2 = 0.f, a3 = 0.f;
#pragma unroll
    for (int k7 = 0; k7 < 7; ++k7) {
      ushort4 vv = *(const ushort4*)(vL + (qt + k7) * 264 + lane * 4);
      a0 += pw[k7] * bf2f(vv.x);
      a1 += pw[k7] * bf2f(vv.y);
      a2 += pw[k7] * bf2f(vv.z);
      a3 += pw[k7] * bf2f(vv.w);
    }
    a0 *= inv; a1 *= inv; a2 *= inv; a3 *= inv;

    float nn = wave_sum(a0 * a0 + a1 * a1 + a2 * a2 + a3 * a3);
    float norm = fmaxf(sqrtf(nn), 1e-7f);
    float sc2 = sinhf(norm) / norm;

    float* orow = out + ((size_t)((b * T_ + t) * J_ + j)) * 257;
    orow[1 + lane * 4] = a0 * sc2;
    orow[2 + lane * 4] = a1 * sc2;
    orow[3 + lane * 4] = a2 * sc2;
    orow[4 + lane * 4] = a3 * sc2;
    if (lane == 0) orow[0] = coshf(norm);
  }
}

// ---------------------------------------------------------------------------
extern "C" void kernel_launch(void* const* d_in, const int* in_sizes, int n_in,
                              void* d_out, int out_size, void* d_ws, size_t ws_size,
                              hipStream_t stream) {
  const float* x   = (const float*)d_in[0];
  // d_in[1] = vel_seq: unused by the reference
  const float* tau = (const float*)d_in[2];
  const float* Wq  = (const float*)d_in[3];
  const float* bq  = (const float*)d_in[4];
  const float* Wk  = (const float*)d_in[5];
  const float* bk  = (const float*)d_in[6];
  const float* Wv  = (const float*)d_in[7];
  const float* bv  = (const float*)d_in[8];
  float* out = (float*)d_out;

  char* ws = (char*)d_ws;
  unsigned short* wv  = (unsigned short*)(ws);            // 131072 B
  unsigned short* gtb = (unsigned short*)(ws + 131072);   // 131072 B
  float* w1v  = (float*)(ws + 262144);                    // 1024 B
  float* w2v  = (float*)(ws + 263168);                    // 1024 B
  float* bqkp = (float*)(ws + 264192);                    // 16 B

  wv_kernel<<<dim3(256), dim3(256), 0, stream>>>(Wv, wv);
  gram_kernel<<<dim3(256), dim3(256), 0, stream>>>(Wq, Wk, gtb);
  wvec_kernel<<<dim3(1), dim3(256), 0, stream>>>(Wq, Wk, bq, bk, w1v, w2v, bqkp);
  fused_kernel<<<dim3(NCH, BJ_), dim3(256), 0, stream>>>(
      x, wv, gtb, w1v, w2v, bqkp, bv, tau, out);
}